// Round 13
// baseline (64.420 us; speedup 1.0000x reference)
//
#include <hip/hip_runtime.h>
#include <cstdint>
#include <cstddef>

#define N_ENT 100000
#define DIM 128
#define BSZ 256
#define FSZ 20000
#define BM 64
#define NBT 1563             // ceil(N_ENT / 64) row-tiles
#define NSCAN 79             // ceil(FSZ / 256) f-major scan blocks
#define MCAP_B 64            // per-b match segment capacity

typedef __attribute__((ext_vector_type(8))) short bf16x8;
typedef __attribute__((ext_vector_type(4))) float f32x4;

#define KEEP(x) asm volatile("" : "+v"(x))

// ---------------- ws layout (16B-aligned offsets) ----------------
#define WS_QALL   0                                  // [512][128] f32 exact queries
#define WS_QSQ    262144                             // [512] f32
#define WS_THR    264192                             // [512] f32
#define WS_THC    266240                             // [512] f32 (thr-qsq)*0.5
#define WS_CNT    268288                             // [512] int (atomic fallback)
#define WS_PERCNT 270336                             // [256] int per-b match counts
#define WS_MATCH  271360                             // [256][MCAP_B] int2 {side, id}
#define WS_QBF    402432                             // [512][128] bf16 row-major (fallback)
#define WS_QBFP   533504                             // [32][4][64][8] bf16 fragment-major
#define WS_PART   664576                             // [NBT][512] u16
#define WS_NEED   (WS_PART + NBT * 512 * 2)          // ~2.3 MB

__device__ inline unsigned short f2bf(float x) {
    union { float f; uint32_t u; } v; v.f = x;
    uint32_t u = v.u;
    u += 0x7fffu + ((u >> 16) & 1);   // RNE
    return (unsigned short)(u >> 16);
}

// ---- fused front: [0,NSCAN) f-major scanf | [NSCAN,NSCAN+256) prep ----------
__global__ __launch_bounds__(256) void k_front(
    const float* __restrict__ ent, const float* __restrict__ rel,
    const int* __restrict__ heads, const int* __restrict__ rels, const int* __restrict__ tails,
    const int* __restrict__ fh, const int* __restrict__ fr, const int* __restrict__ ft,
    float* __restrict__ qall, float* __restrict__ qsq, float* __restrict__ thr,
    float* __restrict__ thc, int* __restrict__ cnt,
    unsigned short* __restrict__ qbf, unsigned short* __restrict__ qbfp,
    int* __restrict__ percnt, int2* __restrict__ match)
{
    int bid = blockIdx.x;
    int tid = threadIdx.x;

    if (bid < NSCAN) {
        // ---- scanf, f-major: thread owns one f; b-keys broadcast from LDS ---
        __shared__ int k1[BSZ], k2[BSZ];
        k1[tid] = rels[tid] * 100000 + tails[tid];   // head-side key (r,t)
        k2[tid] = rels[tid] * 100000 + heads[tid];   // tail-side key (r,h)
        __syncthreads();
        int f = bid * 256 + tid;
        if (f < FSZ) {
            int vr = fr[f], vt = ft[f], vh = fh[f];
            int fk1 = vr * 100000 + vt;
            int fk2 = vr * 100000 + vh;
            #pragma unroll 8
            for (int b = 0; b < BSZ; b++) {
                if (fk1 == k1[b]) {
                    int p = atomicAdd(&percnt[b], 1);
                    if (p < MCAP_B) match[b * MCAP_B + p] = make_int2(0, vh);
                }
                if (fk2 == k2[b]) {
                    int p = atomicAdd(&percnt[b], 1);
                    if (p < MCAP_B) match[b * MCAP_B + p] = make_int2(1, vt);
                }
            }
        }
        return;
    }

    // ---------------- prep: single wave, lane owns dims d and d+64 -----------
    if (tid >= 64) return;                        // no barriers below: safe
    int b = bid - NSCAN;
    int h = heads[b], r = rels[b], t = tails[b];
    float s0 = 0.f, s1 = 0.f, s2 = 0.f;
    #pragma unroll
    for (int half = 0; half < 2; half++) {
        int d = tid + half * 64;
        float eh = ent[(size_t)h * DIM + d];
        float er = rel[(size_t)r * DIM + d];
        float et = ent[(size_t)t * DIM + d];
        float diff = eh + er - et;
        float q = er - et;
        float p = eh + er;
        qall[(size_t)b * DIM + d] = q;
        qall[(size_t)(BSZ + b) * DIM + d] = -p;
        unsigned short qb16 = f2bf(q), pb16 = f2bf(-p);
        qbf[(size_t)b * DIM + d] = qb16;
        qbf[(size_t)(BSZ + b) * DIM + d] = pb16;
        int ks = d >> 5, kq = (d >> 3) & 3, e = d & 7;
        int l0 = kq * 16 + (b & 15);
        int c0 = b >> 4, c1 = (BSZ + b) >> 4;
        qbfp[(size_t)((c0 * 4 + ks) * 64 + l0) * 8 + e] = qb16;
        qbfp[(size_t)((c1 * 4 + ks) * 64 + l0) * 8 + e] = pb16;
        s0 += diff * diff; s1 += q * q; s2 += p * p;
    }
    #pragma unroll
    for (int off = 32; off; off >>= 1) {
        s0 += __shfl_xor(s0, off);
        s1 += __shfl_xor(s1, off);
        s2 += __shfl_xor(s2, off);
    }
    if (tid == 0) {
        float th = fmaxf(s0, 1e-12f);
        thr[b] = th; thr[BSZ + b] = th;
        qsq[b] = s1; qsq[BSZ + b] = s2;
        thc[b] = (th - s1) * 0.5f;
        thc[BSZ + b] = (th - s2) * 0.5f;
        cnt[b] = 0;  cnt[BSZ + b] = 0;
    }
}

// MFMA count: 4-wave blocks, wave w owns row-tile bt = blockIdx*4 + w.
// A loaded directly from ent (divergent but CL-covered), esq via shfl, folded
// into accumulator init. B streamed lane-contiguous from qbfp (L1-shared),
// 2-deep prefetch. Packed register counts, one 1KB u16 flush per wave.
__global__ __launch_bounds__(256, 2) void k_count(
    const float* __restrict__ ent,
    const unsigned short* __restrict__ qbfp, const float* __restrict__ thc,
    unsigned short* __restrict__ part)
{
    int tid = threadIdx.x;
    int l = tid & 63;
    int bt = blockIdx.x * 4 + (tid >> 6);
    if (bt >= NBT) return;
    int koff = (l >> 4) * 8;                 // k-quarter owned by this lane

    bf16x8 a[4][4];
    float hsq[4];
    #pragma unroll
    for (int s = 0; s < 4; s++) {
        int n = bt * BM + s * 16 + (l & 15);
        bool valid = n < N_ENT;
        const float* rowp = ent + (size_t)(valid ? n : (N_ENT - 1)) * DIM + koff;
        float ss = 0.f;
        #pragma unroll
        for (int ks = 0; ks < 4; ks++) {
            float4 u0 = *(const float4*)(rowp + ks * 32);
            float4 u1 = *(const float4*)(rowp + ks * 32 + 4);
            ss += u0.x*u0.x + u0.y*u0.y + u0.z*u0.z + u0.w*u0.w
                + u1.x*u1.x + u1.y*u1.y + u1.z*u1.z + u1.w*u1.w;
            bf16x8 f;
            f[0]=(short)f2bf(u0.x); f[1]=(short)f2bf(u0.y); f[2]=(short)f2bf(u0.z); f[3]=(short)f2bf(u0.w);
            f[4]=(short)f2bf(u1.x); f[5]=(short)f2bf(u1.y); f[6]=(short)f2bf(u1.z); f[7]=(short)f2bf(u1.w);
            a[s][ks] = f;
        }
        ss += __shfl_xor(ss, 16);
        ss += __shfl_xor(ss, 32);
        hsq[s] = valid ? ss * 0.5f : 1.5e38f;   // 0.5*||row||^2, inf for pad rows
    }
    f32x4 ehv[4];
    #pragma unroll
    for (int s = 0; s < 4; s++)
        #pragma unroll
        for (int r = 0; r < 4; r++)
            ehv[s][r] = __shfl(hsq[s], (l >> 4) * 4 + r);

    bf16x8 bcur[4], bn1[4], bn2[4];
    #pragma unroll
    for (int ks = 0; ks < 4; ks++) {
        bcur[ks] = *(const bf16x8*)(qbfp + ((size_t)(0 * 4 + ks) * 64 + l) * 8);
        bn1[ks]  = *(const bf16x8*)(qbfp + ((size_t)(1 * 4 + ks) * 64 + l) * 8);
    }
    float tc  = thc[l & 15];
    float tn1 = thc[16 + (l & 15)];
    float tn2;

    uint32_t creg[8] = {0, 0, 0, 0, 0, 0, 0, 0};

    #pragma unroll
    for (int c = 0; c < 32; c++) {
        // liveness tie: forbid rematerializing a[]/ehv[] from memory
        #pragma unroll
        for (int s = 0; s < 4; s++) {
            KEEP(ehv[s]);
            #pragma unroll
            for (int ks = 0; ks < 4; ks++) KEEP(a[s][ks]);
        }
        if (c < 30) {
            #pragma unroll
            for (int ks = 0; ks < 4; ks++)
                bn2[ks] = *(const bf16x8*)(qbfp + ((size_t)((c + 2) * 4 + ks) * 64 + l) * 8);
            tn2 = thc[(c + 2) * 16 + (l & 15)];
        }
        f32x4 acc[4];
        #pragma unroll
        for (int s = 0; s < 4; s++)   // esq enters via the C operand
            acc[s] = __builtin_amdgcn_mfma_f32_16x16x32_bf16(a[s][0], bcur[0], ehv[s], 0, 0, 0);
        #pragma unroll
        for (int ks = 1; ks < 4; ks++)
            #pragma unroll
            for (int s = 0; s < 4; s++)
                acc[s] = __builtin_amdgcn_mfma_f32_16x16x32_bf16(a[s][ks], bcur[ks], acc[s], 0, 0, 0);
        uint32_t cl = 0;
        #pragma unroll
        for (int s = 0; s < 4; s++)
            #pragma unroll
            for (int r = 0; r < 4; r++)
                cl += (acc[s][r] < tc) ? 1u : 0u;   // esqh + dot < (thr-qsq)/2
        creg[c >> 2] += cl << (8 * (c & 3));
        tc = tn1; tn1 = tn2;
        #pragma unroll
        for (int ks = 0; ks < 4; ks++) { bcur[ks] = bn1[ks]; bn1[ks] = bn2[ks]; }
    }

    #pragma unroll
    for (int i = 0; i < 8; i++) {
        uint32_t x = creg[i];
        x += __shfl_xor(x, 16);
        x += __shfl_xor(x, 32);
        creg[i] = x;
    }
    if (l < 16) {
        #pragma unroll
        for (int c = 0; c < 32; c++)
            part[(size_t)bt * 512 + c * 16 + l] =
                (unsigned short)((creg[c >> 2] >> (8 * (c & 3))) & 0xffu);
    }
}

// Fallback path (round-6 proven) when ws is too small for part.
__global__ __launch_bounds__(128, 3) void k_count_fb(
    const float* __restrict__ ent,
    const unsigned short* __restrict__ qbf,
    const float* __restrict__ thc,
    int* __restrict__ cnt)
{
    int tid = threadIdx.x;
    int lane = tid & 63, wave = tid >> 6;
    int base = blockIdx.x * BM;
    int koff = (lane >> 4) * 8;
    int colq = wave * 256 + (lane & 15);
    const unsigned short* qb = qbf + (size_t)colq * DIM + koff;
    bf16x8 bcur[4], bnext[4];
    #pragma unroll
    for (int ks = 0; ks < 4; ks++) bcur[ks] = *(const bf16x8*)(qb + ks * 32);
    bf16x8 a[4][4];
    float hsq[4];
    #pragma unroll
    for (int s = 0; s < 4; s++) {
        int n = base + s * 16 + (lane & 15);
        bool valid = n < N_ENT;
        const float* rowp = ent + (size_t)(valid ? n : (N_ENT - 1)) * DIM + koff;
        float ss = 0.f;
        #pragma unroll
        for (int ks = 0; ks < 4; ks++) {
            float4 u0 = *(const float4*)(rowp + ks * 32);
            float4 u1 = *(const float4*)(rowp + ks * 32 + 4);
            ss += u0.x*u0.x + u0.y*u0.y + u0.z*u0.z + u0.w*u0.w
                + u1.x*u1.x + u1.y*u1.y + u1.z*u1.z + u1.w*u1.w;
            bf16x8 f;
            f[0]=(short)f2bf(u0.x); f[1]=(short)f2bf(u0.y); f[2]=(short)f2bf(u0.z); f[3]=(short)f2bf(u0.w);
            f[4]=(short)f2bf(u1.x); f[5]=(short)f2bf(u1.y); f[6]=(short)f2bf(u1.z); f[7]=(short)f2bf(u1.w);
            a[s][ks] = f; KEEP(a[s][ks]);
        }
        ss += __shfl_xor(ss, 16); ss += __shfl_xor(ss, 32);
        hsq[s] = valid ? ss * 0.5f : 1.5e38f;
    }
    float eh[4][4];
    #pragma unroll
    for (int s = 0; s < 4; s++)
        #pragma unroll
        for (int r = 0; r < 4; r++) { eh[s][r] = __shfl(hsq[s], (lane >> 4) * 4 + r); KEEP(eh[s][r]); }
    #pragma unroll
    for (int c = 0; c < 16; c++) {
        if (c < 15) {
            #pragma unroll
            for (int ks = 0; ks < 4; ks++)
                bnext[ks] = *(const bf16x8*)(qb + (size_t)(c + 1) * 16 * DIM + ks * 32);
        }
        float tcv = thc[colq + c * 16];
        f32x4 acc[4];
        #pragma unroll
        for (int s = 0; s < 4; s++) acc[s] = (f32x4){0.f, 0.f, 0.f, 0.f};
        #pragma unroll
        for (int ks = 0; ks < 4; ks++)
            #pragma unroll
            for (int s = 0; s < 4; s++)
                acc[s] = __builtin_amdgcn_mfma_f32_16x16x32_bf16(a[s][ks], bcur[ks], acc[s], 0, 0, 0);
        int cl = 0;
        #pragma unroll
        for (int s = 0; s < 4; s++)
            #pragma unroll
            for (int r = 0; r < 4; r++)
                cl += (acc[s][r] < tcv - eh[s][r]) ? 1 : 0;
        cl += __shfl_xor(cl, 16);
        cl += __shfl_xor(cl, 32);
        if (lane < 16) atomicAdd(&cnt[colq + c * 16], cl);
        #pragma unroll
        for (int ks = 0; ks < 4; ks++) bcur[ks] = bnext[ks];
    }
}

// Per (side,b)=key: strided sum of the part column (L2-hot), per-b match
// segment gather, dedup, exact fp32 recompute, rank = sum + 1 - adj.
__global__ __launch_bounds__(256) void k_adjust(
    const float* __restrict__ ent,
    const float* __restrict__ qall, const float* __restrict__ qsq, const float* __restrict__ thr,
    const int* __restrict__ cnt, const unsigned short* __restrict__ part, int use_part,
    const int* __restrict__ percnt, const int2* __restrict__ match,
    int* __restrict__ out)
{
    int key = blockIdx.x;
    int side = key >> 8, b = key & 255;
    int tid = threadIdx.x;
    __shared__ int ids[MCAP_B];
    __shared__ int nm;
    __shared__ int wsum[4];
    if (tid == 0) nm = 0;
    __syncthreads();

    int acc = 0;
    if (use_part) {
        for (int i = tid; i < NBT; i += 256)
            acc += part[(size_t)i * 512 + key];
    } else if (tid == 0) {
        acc = cnt[key];
    }

    int M = percnt[b];
    if (M > MCAP_B) M = MCAP_B;
    if (tid < M) {
        int2 e = match[b * MCAP_B + tid];
        if (e.x == side) { int p = atomicAdd(&nm, 1); ids[p] = e.y; }
    }
    __syncthreads();
    int mm = nm;
    const float* qv = qall + (size_t)key * DIM;
    float qq = qsq[key], th = thr[key];
    for (int i = tid; i < mm; i += 256) {
        int id = ids[i];
        bool dup = false;
        for (int j = 0; j < i; j++) if (ids[j] == id) { dup = true; break; }
        if (!dup) {
            const float* en = ent + (size_t)id * DIM;
            float es = 0.f, dot = 0.f;
            for (int d = 0; d < DIM; d++) { float x = en[d]; es += x * x; dot += x * qv[d]; }
            if (fmaxf(es + 2.f * dot + qq, 1e-12f) < th) acc--;
        }
    }
    #pragma unroll
    for (int off = 32; off; off >>= 1) acc += __shfl_xor(acc, off);
    int lane = tid & 63, wv = tid >> 6;
    if (lane == 0) wsum[wv] = acc;
    __syncthreads();
    if (tid == 0) out[key] = wsum[0] + wsum[1] + wsum[2] + wsum[3] + 1;
}

extern "C" void kernel_launch(void* const* d_in, const int* in_sizes, int n_in,
                              void* d_out, int out_size, void* d_ws, size_t ws_size,
                              hipStream_t stream)
{
    const float* ent   = (const float*)d_in[0];
    const float* rel   = (const float*)d_in[1];
    const int*   heads = (const int*)d_in[2];
    const int*   rels  = (const int*)d_in[3];
    const int*   tails = (const int*)d_in[4];
    const int*   fh    = (const int*)d_in[5];
    const int*   fr    = (const int*)d_in[6];
    const int*   ft    = (const int*)d_in[7];
    int* out = (int*)d_out;

    char* ws = (char*)d_ws;
    float* qall = (float*)(ws + WS_QALL);
    float* qsq  = (float*)(ws + WS_QSQ);
    float* thr  = (float*)(ws + WS_THR);
    float* thc  = (float*)(ws + WS_THC);
    int*   cnt  = (int*)(ws + WS_CNT);
    int*   percnt = (int*)(ws + WS_PERCNT);
    int2*  match  = (int2*)(ws + WS_MATCH);
    unsigned short* qbf   = (unsigned short*)(ws + WS_QBF);
    unsigned short* qbfp  = (unsigned short*)(ws + WS_QBFP);
    unsigned short* part  = (unsigned short*)(ws + WS_PART);

    int use_part = (ws_size >= (size_t)WS_NEED) ? 1 : 0;

    hipMemsetAsync(percnt, 0, BSZ * sizeof(int), stream);
    k_front<<<NSCAN + BSZ, 256, 0, stream>>>(ent, rel, heads, rels, tails, fh, fr, ft,
                                             qall, qsq, thr, thc, cnt, qbf, qbfp,
                                             percnt, match);
    if (use_part)
        k_count<<<(NBT + 3) / 4, 256, 0, stream>>>(ent, qbfp, thc, part);
    else
        k_count_fb<<<NBT, 128, 0, stream>>>(ent, qbf, thc, cnt);
    k_adjust<<<2 * BSZ, 256, 0, stream>>>(ent, qall, qsq, thr, cnt, part, use_part,
                                          percnt, match, out);
}

// Round 14
// 59.087 us; speedup vs baseline: 1.0903x; 1.0903x over previous
//
#include <hip/hip_runtime.h>
#include <cstdint>
#include <cstddef>

#define N_ENT 100000
#define DIM 128
#define BSZ 256
#define FSZ 20000
#define BM 64
#define NBT 1563             // ceil(N_ENT / 64) row-tiles
#define NSCAN 79             // ceil(FSZ / 256) f-major scan blocks
#define GCAP 64              // per-scan-block match segment capacity
#define MCAP_B 64            // per-key LDS id-list capacity in k_adjust

typedef __attribute__((ext_vector_type(8))) short bf16x8;
typedef __attribute__((ext_vector_type(4))) float f32x4;

#define KEEP(x) asm volatile("" : "+v"(x))

// ---------------- ws layout (16B-aligned offsets) ----------------
#define WS_QALL   0                                  // [512][128] f32 exact queries
#define WS_QSQ    262144                             // [512] f32
#define WS_THR    264192                             // [512] f32
#define WS_THC    266240                             // [512] f32 (thr-qsq)*0.5
#define WS_CNT    268288                             // [512] int (atomic fallback)
#define WS_GCNT   270336                             // [NSCAN] int (written every launch)
#define WS_MATCH  270656                             // [NSCAN][GCAP] int2 {key, id}
#define WS_QBF    311104                             // [512][128] bf16 row-major (fallback)
#define WS_QBFP   442176                             // [32][4][64][8] bf16 fragment-major
#define WS_PART   573248                             // [NBT][512] u16
#define WS_NEED   (WS_PART + NBT * 512 * 2)          // ~2.2 MB

__device__ inline unsigned short f2bf(float x) {
    union { float f; uint32_t u; } v; v.f = x;
    uint32_t u = v.u;
    u += 0x7fffu + ((u >> 16) & 1);   // RNE
    return (unsigned short)(u >> 16);
}

// ---- fused front: [0,NSCAN) f-major scanf | [NSCAN,NSCAN+256) prep ----------
__global__ __launch_bounds__(256) void k_front(
    const float* __restrict__ ent, const float* __restrict__ rel,
    const int* __restrict__ heads, const int* __restrict__ rels, const int* __restrict__ tails,
    const int* __restrict__ fh, const int* __restrict__ fr, const int* __restrict__ ft,
    float* __restrict__ qall, float* __restrict__ qsq, float* __restrict__ thr,
    float* __restrict__ thc, int* __restrict__ cnt,
    unsigned short* __restrict__ qbf, unsigned short* __restrict__ qbfp,
    int* __restrict__ gcnt, int2* __restrict__ gmatch)
{
    int bid = blockIdx.x;
    int tid = threadIdx.x;

    if (bid < NSCAN) {
        // ---- scanf, f-major: thread owns one f; b-keys broadcast from LDS.
        // Matches go to this block's OWN segment (LDS counter — no global init).
        __shared__ int k1[BSZ], k2[BSZ];
        __shared__ int nm;
        if (tid == 0) nm = 0;
        k1[tid] = rels[tid] * 100000 + tails[tid];   // head-side key (r,t)
        k2[tid] = rels[tid] * 100000 + heads[tid];   // tail-side key (r,h)
        __syncthreads();
        int f = bid * 256 + tid;
        if (f < FSZ) {
            int vr = fr[f], vt = ft[f], vh = fh[f];
            int fk1 = vr * 100000 + vt;
            int fk2 = vr * 100000 + vh;
            #pragma unroll 8
            for (int b = 0; b < BSZ; b++) {
                if (fk1 == k1[b]) {
                    int p = atomicAdd(&nm, 1);
                    if (p < GCAP) gmatch[bid * GCAP + p] = make_int2(b, vh);        // head side: key=b
                }
                if (fk2 == k2[b]) {
                    int p = atomicAdd(&nm, 1);
                    if (p < GCAP) gmatch[bid * GCAP + p] = make_int2(BSZ + b, vt);  // tail side: key=256+b
                }
            }
        }
        __syncthreads();
        if (tid == 0) gcnt[bid] = nm < GCAP ? nm : GCAP;   // unconditional store every launch
        return;
    }

    // ---------------- prep: single wave, lane owns dims d and d+64 -----------
    if (tid >= 64) return;                        // no barriers below: safe
    int b = bid - NSCAN;
    int h = heads[b], r = rels[b], t = tails[b];
    float s0 = 0.f, s1 = 0.f, s2 = 0.f;
    #pragma unroll
    for (int half = 0; half < 2; half++) {
        int d = tid + half * 64;
        float eh = ent[(size_t)h * DIM + d];
        float er = rel[(size_t)r * DIM + d];
        float et = ent[(size_t)t * DIM + d];
        float diff = eh + er - et;
        float q = er - et;
        float p = eh + er;
        qall[(size_t)b * DIM + d] = q;
        qall[(size_t)(BSZ + b) * DIM + d] = -p;
        unsigned short qb16 = f2bf(q), pb16 = f2bf(-p);
        qbf[(size_t)b * DIM + d] = qb16;
        qbf[(size_t)(BSZ + b) * DIM + d] = pb16;
        int ks = d >> 5, kq = (d >> 3) & 3, e = d & 7;
        int l0 = kq * 16 + (b & 15);
        int c0 = b >> 4, c1 = (BSZ + b) >> 4;
        qbfp[(size_t)((c0 * 4 + ks) * 64 + l0) * 8 + e] = qb16;
        qbfp[(size_t)((c1 * 4 + ks) * 64 + l0) * 8 + e] = pb16;
        s0 += diff * diff; s1 += q * q; s2 += p * p;
    }
    #pragma unroll
    for (int off = 32; off; off >>= 1) {
        s0 += __shfl_xor(s0, off);
        s1 += __shfl_xor(s1, off);
        s2 += __shfl_xor(s2, off);
    }
    if (tid == 0) {
        float th = fmaxf(s0, 1e-12f);
        thr[b] = th; thr[BSZ + b] = th;
        qsq[b] = s1; qsq[BSZ + b] = s2;
        thc[b] = (th - s1) * 0.5f;
        thc[BSZ + b] = (th - s2) * 0.5f;
        cnt[b] = 0;  cnt[BSZ + b] = 0;
    }
}

// MFMA count: 4-wave blocks, wave w owns row-tile bt = blockIdx*4 + w.
// A loaded directly from ent (divergent but CL-covered), esq via shfl, folded
// into accumulator init. B streamed lane-contiguous from qbfp (L1-shared),
// 2-deep prefetch. Packed register counts, one 1KB u16 flush per wave.
__global__ __launch_bounds__(256, 2) void k_count(
    const float* __restrict__ ent,
    const unsigned short* __restrict__ qbfp, const float* __restrict__ thc,
    unsigned short* __restrict__ part)
{
    int tid = threadIdx.x;
    int l = tid & 63;
    int bt = blockIdx.x * 4 + (tid >> 6);
    if (bt >= NBT) return;
    int koff = (l >> 4) * 8;                 // k-quarter owned by this lane

    bf16x8 a[4][4];
    float hsq[4];
    #pragma unroll
    for (int s = 0; s < 4; s++) {
        int n = bt * BM + s * 16 + (l & 15);
        bool valid = n < N_ENT;
        const float* rowp = ent + (size_t)(valid ? n : (N_ENT - 1)) * DIM + koff;
        float ss = 0.f;
        #pragma unroll
        for (int ks = 0; ks < 4; ks++) {
            float4 u0 = *(const float4*)(rowp + ks * 32);
            float4 u1 = *(const float4*)(rowp + ks * 32 + 4);
            ss += u0.x*u0.x + u0.y*u0.y + u0.z*u0.z + u0.w*u0.w
                + u1.x*u1.x + u1.y*u1.y + u1.z*u1.z + u1.w*u1.w;
            bf16x8 f;
            f[0]=(short)f2bf(u0.x); f[1]=(short)f2bf(u0.y); f[2]=(short)f2bf(u0.z); f[3]=(short)f2bf(u0.w);
            f[4]=(short)f2bf(u1.x); f[5]=(short)f2bf(u1.y); f[6]=(short)f2bf(u1.z); f[7]=(short)f2bf(u1.w);
            a[s][ks] = f;
        }
        ss += __shfl_xor(ss, 16);
        ss += __shfl_xor(ss, 32);
        hsq[s] = valid ? ss * 0.5f : 1.5e38f;   // 0.5*||row||^2, inf for pad rows
    }
    f32x4 ehv[4];
    #pragma unroll
    for (int s = 0; s < 4; s++)
        #pragma unroll
        for (int r = 0; r < 4; r++)
            ehv[s][r] = __shfl(hsq[s], (l >> 4) * 4 + r);

    bf16x8 bcur[4], bn1[4], bn2[4];
    #pragma unroll
    for (int ks = 0; ks < 4; ks++) {
        bcur[ks] = *(const bf16x8*)(qbfp + ((size_t)(0 * 4 + ks) * 64 + l) * 8);
        bn1[ks]  = *(const bf16x8*)(qbfp + ((size_t)(1 * 4 + ks) * 64 + l) * 8);
    }
    float tc  = thc[l & 15];
    float tn1 = thc[16 + (l & 15)];
    float tn2;

    uint32_t creg[8] = {0, 0, 0, 0, 0, 0, 0, 0};

    #pragma unroll
    for (int c = 0; c < 32; c++) {
        // liveness tie: forbid rematerializing a[]/ehv[] from memory
        #pragma unroll
        for (int s = 0; s < 4; s++) {
            KEEP(ehv[s]);
            #pragma unroll
            for (int ks = 0; ks < 4; ks++) KEEP(a[s][ks]);
        }
        if (c < 30) {
            #pragma unroll
            for (int ks = 0; ks < 4; ks++)
                bn2[ks] = *(const bf16x8*)(qbfp + ((size_t)((c + 2) * 4 + ks) * 64 + l) * 8);
            tn2 = thc[(c + 2) * 16 + (l & 15)];
        }
        f32x4 acc[4];
        #pragma unroll
        for (int s = 0; s < 4; s++)   // esq enters via the C operand
            acc[s] = __builtin_amdgcn_mfma_f32_16x16x32_bf16(a[s][0], bcur[0], ehv[s], 0, 0, 0);
        #pragma unroll
        for (int ks = 1; ks < 4; ks++)
            #pragma unroll
            for (int s = 0; s < 4; s++)
                acc[s] = __builtin_amdgcn_mfma_f32_16x16x32_bf16(a[s][ks], bcur[ks], acc[s], 0, 0, 0);
        uint32_t cl = 0;
        #pragma unroll
        for (int s = 0; s < 4; s++)
            #pragma unroll
            for (int r = 0; r < 4; r++)
                cl += (acc[s][r] < tc) ? 1u : 0u;   // esqh + dot < (thr-qsq)/2
        creg[c >> 2] += cl << (8 * (c & 3));
        tc = tn1; tn1 = tn2;
        #pragma unroll
        for (int ks = 0; ks < 4; ks++) { bcur[ks] = bn1[ks]; bn1[ks] = bn2[ks]; }
    }

    #pragma unroll
    for (int i = 0; i < 8; i++) {
        uint32_t x = creg[i];
        x += __shfl_xor(x, 16);
        x += __shfl_xor(x, 32);
        creg[i] = x;
    }
    if (l < 16) {
        #pragma unroll
        for (int c = 0; c < 32; c++)
            part[(size_t)bt * 512 + c * 16 + l] =
                (unsigned short)((creg[c >> 2] >> (8 * (c & 3))) & 0xffu);
    }
}

// Fallback path (round-6 proven) when ws is too small for part.
__global__ __launch_bounds__(128, 3) void k_count_fb(
    const float* __restrict__ ent,
    const unsigned short* __restrict__ qbf,
    const float* __restrict__ thc,
    int* __restrict__ cnt)
{
    int tid = threadIdx.x;
    int lane = tid & 63, wave = tid >> 6;
    int base = blockIdx.x * BM;
    int koff = (lane >> 4) * 8;
    int colq = wave * 256 + (lane & 15);
    const unsigned short* qb = qbf + (size_t)colq * DIM + koff;
    bf16x8 bcur[4], bnext[4];
    #pragma unroll
    for (int ks = 0; ks < 4; ks++) bcur[ks] = *(const bf16x8*)(qb + ks * 32);
    bf16x8 a[4][4];
    float hsq[4];
    #pragma unroll
    for (int s = 0; s < 4; s++) {
        int n = base + s * 16 + (lane & 15);
        bool valid = n < N_ENT;
        const float* rowp = ent + (size_t)(valid ? n : (N_ENT - 1)) * DIM + koff;
        float ss = 0.f;
        #pragma unroll
        for (int ks = 0; ks < 4; ks++) {
            float4 u0 = *(const float4*)(rowp + ks * 32);
            float4 u1 = *(const float4*)(rowp + ks * 32 + 4);
            ss += u0.x*u0.x + u0.y*u0.y + u0.z*u0.z + u0.w*u0.w
                + u1.x*u1.x + u1.y*u1.y + u1.z*u1.z + u1.w*u1.w;
            bf16x8 f;
            f[0]=(short)f2bf(u0.x); f[1]=(short)f2bf(u0.y); f[2]=(short)f2bf(u0.z); f[3]=(short)f2bf(u0.w);
            f[4]=(short)f2bf(u1.x); f[5]=(short)f2bf(u1.y); f[6]=(short)f2bf(u1.z); f[7]=(short)f2bf(u1.w);
            a[s][ks] = f; KEEP(a[s][ks]);
        }
        ss += __shfl_xor(ss, 16); ss += __shfl_xor(ss, 32);
        hsq[s] = valid ? ss * 0.5f : 1.5e38f;
    }
    float eh[4][4];
    #pragma unroll
    for (int s = 0; s < 4; s++)
        #pragma unroll
        for (int r = 0; r < 4; r++) { eh[s][r] = __shfl(hsq[s], (lane >> 4) * 4 + r); KEEP(eh[s][r]); }
    #pragma unroll
    for (int c = 0; c < 16; c++) {
        if (c < 15) {
            #pragma unroll
            for (int ks = 0; ks < 4; ks++)
                bnext[ks] = *(const bf16x8*)(qb + (size_t)(c + 1) * 16 * DIM + ks * 32);
        }
        float tcv = thc[colq + c * 16];
        f32x4 acc[4];
        #pragma unroll
        for (int s = 0; s < 4; s++) acc[s] = (f32x4){0.f, 0.f, 0.f, 0.f};
        #pragma unroll
        for (int ks = 0; ks < 4; ks++)
            #pragma unroll
            for (int s = 0; s < 4; s++)
                acc[s] = __builtin_amdgcn_mfma_f32_16x16x32_bf16(a[s][ks], bcur[ks], acc[s], 0, 0, 0);
        int cl = 0;
        #pragma unroll
        for (int s = 0; s < 4; s++)
            #pragma unroll
            for (int r = 0; r < 4; r++)
                cl += (acc[s][r] < tcv - eh[s][r]) ? 1 : 0;
        cl += __shfl_xor(cl, 16);
        cl += __shfl_xor(cl, 32);
        if (lane < 16) atomicAdd(&cnt[colq + c * 16], cl);
        #pragma unroll
        for (int ks = 0; ks < 4; ks++) bcur[ks] = bnext[ks];
    }
}

// Per (side,b)=key: strided sum of the part column (L2-hot), gather matching
// ids from the NSCAN group segments, dedup, exact fp32 recompute,
// rank = sum + 1 - adj.
__global__ __launch_bounds__(256) void k_adjust(
    const float* __restrict__ ent,
    const float* __restrict__ qall, const float* __restrict__ qsq, const float* __restrict__ thr,
    const int* __restrict__ cnt, const unsigned short* __restrict__ part, int use_part,
    const int* __restrict__ gcnt, const int2* __restrict__ gmatch,
    int* __restrict__ out)
{
    int key = blockIdx.x;
    int tid = threadIdx.x;
    __shared__ int ids[MCAP_B];
    __shared__ int nm;
    __shared__ int wsum[4];
    if (tid == 0) nm = 0;
    __syncthreads();

    int acc = 0;
    if (use_part) {
        for (int i = tid; i < NBT; i += 256)
            acc += part[(size_t)i * 512 + key];
    } else if (tid == 0) {
        acc = cnt[key];
    }

    if (tid < NSCAN) {
        int cg = gcnt[tid];
        if (cg > GCAP) cg = GCAP;
        if (cg < 0) cg = 0;
        for (int i = 0; i < cg; i++) {
            int2 e = gmatch[tid * GCAP + i];
            if (e.x == key) {
                int p = atomicAdd(&nm, 1);
                if (p < MCAP_B) ids[p] = e.y;
            }
        }
    }
    __syncthreads();
    int mm = nm < MCAP_B ? nm : MCAP_B;
    const float* qv = qall + (size_t)key * DIM;
    float qq = qsq[key], th = thr[key];
    for (int i = tid; i < mm; i += 256) {
        int id = ids[i];
        bool dup = false;
        for (int j = 0; j < i; j++) if (ids[j] == id) { dup = true; break; }
        if (!dup) {
            const float* en = ent + (size_t)id * DIM;
            float es = 0.f, dot = 0.f;
            for (int d = 0; d < DIM; d++) { float x = en[d]; es += x * x; dot += x * qv[d]; }
            if (fmaxf(es + 2.f * dot + qq, 1e-12f) < th) acc--;
        }
    }
    #pragma unroll
    for (int off = 32; off; off >>= 1) acc += __shfl_xor(acc, off);
    int lane = tid & 63, wv = tid >> 6;
    if (lane == 0) wsum[wv] = acc;
    __syncthreads();
    if (tid == 0) out[key] = wsum[0] + wsum[1] + wsum[2] + wsum[3] + 1;
}

extern "C" void kernel_launch(void* const* d_in, const int* in_sizes, int n_in,
                              void* d_out, int out_size, void* d_ws, size_t ws_size,
                              hipStream_t stream)
{
    const float* ent   = (const float*)d_in[0];
    const float* rel   = (const float*)d_in[1];
    const int*   heads = (const int*)d_in[2];
    const int*   rels  = (const int*)d_in[3];
    const int*   tails = (const int*)d_in[4];
    const int*   fh    = (const int*)d_in[5];
    const int*   fr    = (const int*)d_in[6];
    const int*   ft    = (const int*)d_in[7];
    int* out = (int*)d_out;

    char* ws = (char*)d_ws;
    float* qall = (float*)(ws + WS_QALL);
    float* qsq  = (float*)(ws + WS_QSQ);
    float* thr  = (float*)(ws + WS_THR);
    float* thc  = (float*)(ws + WS_THC);
    int*   cnt  = (int*)(ws + WS_CNT);
    int*   gcnt = (int*)(ws + WS_GCNT);
    int2*  gmatch = (int2*)(ws + WS_MATCH);
    unsigned short* qbf   = (unsigned short*)(ws + WS_QBF);
    unsigned short* qbfp  = (unsigned short*)(ws + WS_QBFP);
    unsigned short* part  = (unsigned short*)(ws + WS_PART);

    int use_part = (ws_size >= (size_t)WS_NEED) ? 1 : 0;

    k_front<<<NSCAN + BSZ, 256, 0, stream>>>(ent, rel, heads, rels, tails, fh, fr, ft,
                                             qall, qsq, thr, thc, cnt, qbf, qbfp,
                                             gcnt, gmatch);
    if (use_part)
        k_count<<<(NBT + 3) / 4, 256, 0, stream>>>(ent, qbfp, thc, part);
    else
        k_count_fb<<<NBT, 128, 0, stream>>>(ent, qbf, thc, cnt);
    k_adjust<<<2 * BSZ, 256, 0, stream>>>(ent, qall, qsq, thr, cnt, part, use_part,
                                          gcnt, gmatch, out);
}